// Round 5
// baseline (2834.328 us; speedup 1.0000x reference)
//
#include <hip/hip_runtime.h>

typedef unsigned int u32;
typedef unsigned short u16;

// SpMM: out[src[e], :] += att[e] * X[dst[e], :]
// edges int32 (2,E): src = edges[0..E), dst = edges[E..2E)
//
// Round-10: streaming accumulate via true ds_add_f32 (inline asm).
//   Prep pipeline identical to round 9 (hist matrix radix sort, CHUNK=4096).
//   accumulate_stream: per bucket (128 rows) zero a 64 KB fp32 LDS tile,
//   then 32 groups of 32 lanes each stream an unordered contiguous slice of
//   the bucket's edges: broadcast 8-B record, gather permuted-bf16 row
//   (256 B), 4x a*x, 4x ds_add_f32 (fire-and-forget -> no CAS chain, the
//   round-3 failure was HIP atomicAdd lowering to CAS retry loops).
//   Xb permuted (lane l holds feats {l,l+32,l+64,l+96}) -> ds addrs
//   row*512B + (l+32k)*4 -> bank l, 2 lanes/bank = conflict-free.
//   Removes the regroup's 2nd+3rd epack global passes (-51 MB fetch),
//   all row-grouping LDS machinery, and the CAP overflow path.
//   Manual s_waitcnt lgkmcnt(0) before final barrier: compiler cannot
//   track inline-asm DS ops.

constexpr int D_FEAT  = 128;
constexpr int N_NODES = 100000;
constexpr int BROWS   = 128;
constexpr int KB      = (N_NODES + BROWS - 1) / BROWS;   // 782
constexpr int CHUNK   = 4096;
constexpr int NGRP    = 8;      // colscan chunk groups
constexpr int NCONV   = 256;    // extra blocks in prep1 doing X->bf16

typedef float f32x4_v __attribute__((ext_vector_type(4)));
typedef int   i32x2_v __attribute__((ext_vector_type(2)));

__device__ __forceinline__ u32 rne_bf16(float f) {
    u32 u = __float_as_uint(f);
    return (u + 0x7FFFu + ((u >> 16) & 1u)) >> 16;
}

__device__ __forceinline__ void nt_store4(float* p, float x, float y, float z, float w) {
    f32x4_v t; t.x = x; t.y = y; t.z = z; t.w = w;
    __builtin_nontemporal_store(t, (f32x4_v*)p);
}

__device__ __forceinline__ int2 nt_load2(const int2* p) {
    i32x2_v t = __builtin_nontemporal_load((const i32x2_v*)p);
    return make_int2(t.x, t.y);
}

// ---------- 1: fused per-chunk histogram (u16) + X -> permuted bf16 ----------
// Xb[node*32 + l] = uint2 packing feats {l, l+32} in .x and {l+64, l+96} in .y
__global__ __launch_bounds__(512) void prep1(const int* __restrict__ src,
                                             u16* __restrict__ hist, int E, int nchunk,
                                             const float* __restrict__ X,
                                             uint2* __restrict__ Xb, int do_conv) {
    __shared__ u32 h[KB];
    const int blk = blockIdx.x;
    if (blk < nchunk) {
        const int e0 = blk * CHUNK;
        const int e1 = min(e0 + CHUNK, E);
        const int n  = e1 - e0;
        const int nfull = n & ~3;
        for (int i = threadIdx.x; i < KB; i += 512) h[i] = 0;
        __syncthreads();
        for (int o = threadIdx.x * 4; o < nfull; o += 2048) {
            int4 s4 = *(const int4*)(src + e0 + o);
            atomicAdd(&h[s4.x >> 7], 1u);
            atomicAdd(&h[s4.y >> 7], 1u);
            atomicAdd(&h[s4.z >> 7], 1u);
            atomicAdd(&h[s4.w >> 7], 1u);
        }
        for (int o = nfull + threadIdx.x; o < n; o += 512)
            atomicAdd(&h[src[e0 + o] >> 7], 1u);
        __syncthreads();
        u16* row = hist + (size_t)blk * KB;
        for (int i = threadIdx.x; i < KB; i += 512) row[i] = (u16)h[i];
    } else if (do_conv) {
        const int nthreads = (gridDim.x - nchunk) * 512;
        for (int u = (blk - nchunk) * 512 + threadIdx.x; u < N_NODES * 32;
             u += nthreads) {
            const int d = u >> 5, l = u & 31;
            const float* xr = X + (size_t)d * D_FEAT;
            uint2 o;
            o.x = rne_bf16(xr[l])      | (rne_bf16(xr[l + 32]) << 16);
            o.y = rne_bf16(xr[l + 64]) | (rne_bf16(xr[l + 96]) << 16);
            Xb[(size_t)d * 32 + l] = o;
        }
    }
}

// ---------- 2a: per-(bucket, group) prefix over its chunk range ----------
__global__ __launch_bounds__(256) void colscan_a(u16* __restrict__ hist,
                                                 u32* __restrict__ gt,
                                                 int nchunk, int gsz) {
    const int t = blockIdx.x * 256 + threadIdx.x;
    if (t >= KB * NGRP) return;
    const int g = t / KB;
    const int b = t - g * KB;
    const int c0 = g * gsz;
    const int c1 = min(c0 + gsz, nchunk);
    u32 run = 0;
    int c = c0;
    for (; c + 4 <= c1; c += 4) {
        u32 v0 = hist[(size_t)(c + 0) * KB + b];
        u32 v1 = hist[(size_t)(c + 1) * KB + b];
        u32 v2 = hist[(size_t)(c + 2) * KB + b];
        u32 v3 = hist[(size_t)(c + 3) * KB + b];
        hist[(size_t)(c + 0) * KB + b] = (u16)run;
        hist[(size_t)(c + 1) * KB + b] = (u16)(run + v0);
        hist[(size_t)(c + 2) * KB + b] = (u16)(run + v0 + v1);
        hist[(size_t)(c + 3) * KB + b] = (u16)(run + v0 + v1 + v2);
        run += v0 + v1 + v2 + v3;
    }
    for (; c < c1; ++c) {
        u32 v = hist[(size_t)c * KB + b];
        hist[(size_t)c * KB + b] = (u16)run;
        run += v;
    }
    gt[(size_t)g * KB + b] = run;
}

// ---------- 2b (1 block): per-bucket group bases + exclusive bucket scan ----------
__global__ __launch_bounds__(1024) void colscan_b(const u32* __restrict__ gt,
                                                  u32* __restrict__ gbase,
                                                  u32* __restrict__ bptr) {
    __shared__ u32 s[1024];
    const int t = threadIdx.x;
    u32 tot = 0;
    if (t < KB) {
        #pragma unroll
        for (int g = 0; g < NGRP; ++g) {
            u32 v = gt[(size_t)g * KB + t];
            gbase[(size_t)g * KB + t] = tot;
            tot += v;
        }
    }
    s[t] = tot;
    __syncthreads();
    for (int o = 1; o < 1024; o <<= 1) {
        u32 v = (t >= o) ? s[t - o] : 0u;
        __syncthreads();
        s[t] += v;
        __syncthreads();
    }
    if (t < KB) bptr[t] = s[t] - tot;
    if (t == 1023) bptr[KB] = s[1023];
}

// ---------- 3: scatter with precomputed LDS cursors ----------
__global__ __launch_bounds__(512) void chunk_scatter(const int* __restrict__ src,
                                                     const int* __restrict__ dst,
                                                     const float* __restrict__ att,
                                                     const u32* __restrict__ bptr,
                                                     const u16* __restrict__ hist,
                                                     const u32* __restrict__ gbase,
                                                     int2* __restrict__ epack,
                                                     int E, int gsz) {
    __shared__ u32 cur[KB];
    const int c  = blockIdx.x;
    const int e0 = c * CHUNK;
    const int e1 = min(e0 + CHUNK, E);
    const int n  = e1 - e0;
    const int nfull = n & ~3;
    const u16* hrow = hist + (size_t)c * KB;
    const u32* grow = gbase + (size_t)(c / gsz) * KB;
    for (int i = threadIdx.x; i < KB; i += 512)
        cur[i] = bptr[i] + grow[i] + (u32)hrow[i];
    __syncthreads();
    const bool v4ok = ((E & 3) == 0);   // dst = edges+E alignment for int4
    if (v4ok) {
        for (int o = threadIdx.x * 4; o < nfull; o += 2048) {
            int4   s4 = *(const int4*)(src + e0 + o);
            int4   d4 = *(const int4*)(dst + e0 + o);
            float4 a4 = *(const float4*)(att + e0 + o);
            #pragma unroll
            for (int k = 0; k < 4; ++k) {
                int s = (&s4.x)[k];
                u32 pos = atomicAdd(&cur[s >> 7], 1u);
                epack[pos] = make_int2(((s & 127) << 17) | (&d4.x)[k],
                                       __float_as_int((&a4.x)[k]));
            }
        }
        for (int o = nfull + threadIdx.x; o < n; o += 512) {
            int s = src[e0 + o];
            u32 pos = atomicAdd(&cur[s >> 7], 1u);
            epack[pos] = make_int2(((s & 127) << 17) | dst[e0 + o],
                                   __float_as_int(att[e0 + o]));
        }
    } else {
        for (int o = threadIdx.x; o < n; o += 512) {
            int s = src[e0 + o];
            u32 pos = atomicAdd(&cur[s >> 7], 1u);
            epack[pos] = make_int2(((s & 127) << 17) | dst[e0 + o],
                                   __float_as_int(att[e0 + o]));
        }
    }
}

// ---------- 4 (bf16): streaming ds_add_f32 accumulate ----------
__global__ __launch_bounds__(1024, 8) void accumulate_stream_bf16(
    const u32* __restrict__ bptr, const int2* __restrict__ epack,
    const uint2* __restrict__ Xb, float* __restrict__ out, int N)
{
    __shared__ float acc[BROWS * D_FEAT];   // 64 KB
    const int b   = blockIdx.x;
    const int tid = threadIdx.x;
    const int g   = tid >> 5;               // 32 groups of 32 lanes
    const int l   = tid & 31;
    const u32 s  = bptr[b];
    const u32 nb = bptr[b + 1] - s;
    const int row0 = b * BROWS;
    const int rows = min(BROWS, N - row0);

    for (int i = tid; i < BROWS * 32; i += 1024)
        ((float4*)acc)[i] = make_float4(0.f, 0.f, 0.f, 0.f);
    __syncthreads();

    // LDS byte address base for this lane (low 32 bits of generic = LDS offset)
    const u32 base = (u32)(size_t)acc + ((u32)l << 2);
    const u32 j0 = s + (nb * (u32)g) / 32;
    const u32 j1 = s + (nb * (u32)(g + 1)) / 32;
    u32 j = j0;
    for (; j + 8 <= j1; j += 8) {
        int2 p[8]; uint2 q[8];
        #pragma unroll
        for (int k = 0; k < 8; ++k) p[k] = nt_load2(epack + j + k);
        #pragma unroll
        for (int k = 0; k < 8; ++k) q[k] = Xb[(size_t)(p[k].x & 0x1FFFF) * 32 + l];
        #pragma unroll
        for (int k = 0; k < 8; ++k) {
            const float a = __int_as_float(p[k].y);
            const u32 ad = base + (((u32)p[k].x >> 17) << 9);  // row*512 B
            const float v0 = a * __uint_as_float(q[k].x << 16);
            const float v1 = a * __uint_as_float(q[k].x & 0xFFFF0000u);
            const float v2 = a * __uint_as_float(q[k].y << 16);
            const float v3 = a * __uint_as_float(q[k].y & 0xFFFF0000u);
            asm volatile("ds_add_f32 %0, %1"            :: "v"(ad), "v"(v0));
            asm volatile("ds_add_f32 %0, %1 offset:128" :: "v"(ad), "v"(v1));
            asm volatile("ds_add_f32 %0, %1 offset:256" :: "v"(ad), "v"(v2));
            asm volatile("ds_add_f32 %0, %1 offset:384" :: "v"(ad), "v"(v3));
        }
    }
    for (; j < j1; ++j) {
        const int2 p = nt_load2(epack + j);
        const uint2 q = Xb[(size_t)(p.x & 0x1FFFF) * 32 + l];
        const float a = __int_as_float(p.y);
        const u32 ad = base + (((u32)p.x >> 17) << 9);
        const float v0 = a * __uint_as_float(q.x << 16);
        const float v1 = a * __uint_as_float(q.x & 0xFFFF0000u);
        const float v2 = a * __uint_as_float(q.y << 16);
        const float v3 = a * __uint_as_float(q.y & 0xFFFF0000u);
        asm volatile("ds_add_f32 %0, %1"            :: "v"(ad), "v"(v0));
        asm volatile("ds_add_f32 %0, %1 offset:128" :: "v"(ad), "v"(v1));
        asm volatile("ds_add_f32 %0, %1 offset:256" :: "v"(ad), "v"(v2));
        asm volatile("ds_add_f32 %0, %1 offset:384" :: "v"(ad), "v"(v3));
    }
    // compiler cannot see inline-asm DS ops: drain before the barrier
    asm volatile("s_waitcnt lgkmcnt(0)" ::: "memory");
    __syncthreads();

    // coalesced store: thread -> (row, 4-feat chunk); feats are linear in acc
    for (int i = tid; i < rows * 32; i += 1024) {
        const int r = i >> 5, l2 = i & 31;
        float4 v = *(const float4*)&acc[(r << 7) + (l2 << 2)];
        nt_store4(out + (size_t)(row0 + r) * D_FEAT + (l2 << 2),
                  v.x, v.y, v.z, v.w);
    }
}

// ---------- 4 (fp32): fallback when ws can't hold Xb ----------
__global__ __launch_bounds__(1024, 8) void accumulate_stream_f32(
    const u32* __restrict__ bptr, const int2* __restrict__ epack,
    const float* __restrict__ X, float* __restrict__ out, int N)
{
    __shared__ float acc[BROWS * D_FEAT];
    const int b   = blockIdx.x;
    const int tid = threadIdx.x;
    const int g   = tid >> 5;
    const int l   = tid & 31;
    const u32 s  = bptr[b];
    const u32 nb = bptr[b + 1] - s;
    const int row0 = b * BROWS;
    const int rows = min(BROWS, N - row0);
    const float4* __restrict__ X4 = (const float4*)X;

    for (int i = tid; i < BROWS * 32; i += 1024)
        ((float4*)acc)[i] = make_float4(0.f, 0.f, 0.f, 0.f);
    __syncthreads();

    const u32 base = (u32)(size_t)acc + ((u32)l << 4);
    const u32 j0 = s + (nb * (u32)g) / 32;
    const u32 j1 = s + (nb * (u32)(g + 1)) / 32;
    for (u32 j = j0; j < j1; ++j) {
        const int2 p = nt_load2(epack + j);
        const float4 v = X4[(size_t)(p.x & 0x1FFFF) * 32 + l];
        const float a = __int_as_float(p.y);
        const u32 ad = base + (((u32)p.x >> 17) << 9);
        const float v0 = a * v.x, v1 = a * v.y, v2 = a * v.z, v3 = a * v.w;
        asm volatile("ds_add_f32 %0, %1"           :: "v"(ad), "v"(v0));
        asm volatile("ds_add_f32 %0, %1 offset:4"  :: "v"(ad), "v"(v1));
        asm volatile("ds_add_f32 %0, %1 offset:8"  :: "v"(ad), "v"(v2));
        asm volatile("ds_add_f32 %0, %1 offset:12" :: "v"(ad), "v"(v3));
    }
    asm volatile("s_waitcnt lgkmcnt(0)" ::: "memory");
    __syncthreads();

    for (int i = tid; i < rows * 32; i += 1024) {
        const int r = i >> 5, l2 = i & 31;
        float4 v = *(const float4*)&acc[(r << 7) + (l2 << 2)];
        nt_store4(out + (size_t)(row0 + r) * D_FEAT + (l2 << 2),
                  v.x, v.y, v.z, v.w);
    }
}

// ---------- last-resort fallback: edge-parallel fp atomics ----------
__global__ __launch_bounds__(256) void spmm_edge_atomic(
    const int* __restrict__ src, const int* __restrict__ dst,
    const float* __restrict__ att, const float* __restrict__ X,
    float* __restrict__ out, int E)
{
    const int group = (int)((blockIdx.x * blockDim.x + threadIdx.x) >> 5);
    const int lane  = threadIdx.x & 31;
    const int nGroups = (int)((gridDim.x * blockDim.x) >> 5);
    for (int e = group; e < E; e += nGroups) {
        const int s = src[e], d = dst[e];
        const float a = att[e];
        const float4 v = ((const float4*)(X + (size_t)d * D_FEAT))[lane];
        float* o = out + (size_t)s * D_FEAT + (size_t)lane * 4;
        unsafeAtomicAdd(o + 0, a * v.x);
        unsafeAtomicAdd(o + 1, a * v.y);
        unsafeAtomicAdd(o + 2, a * v.z);
        unsafeAtomicAdd(o + 3, a * v.w);
    }
}

static inline size_t align16(size_t x) { return (x + 15) & ~(size_t)15; }

extern "C" void kernel_launch(void* const* d_in, const int* in_sizes, int n_in,
                              void* d_out, int out_size, void* d_ws, size_t ws_size,
                              hipStream_t stream) {
    const int*   edges = (const int*)d_in[0];   // (2, E) int32
    const float* att   = (const float*)d_in[1]; // (E,)
    const float* X     = (const float*)d_in[3]; // (N, 128)
    float*       out   = (float*)d_out;

    const int E = in_sizes[1];
    const int N = N_NODES;
    const int* src = edges;
    const int* dst = edges + E;
    const int nchunk = (E + CHUNK - 1) / CHUNK;
    const int gsz    = (nchunk + NGRP - 1) / NGRP;

    size_t o_hist  = 0;
    size_t o_gt    = align16(o_hist + (size_t)nchunk * KB * 2);   // u16 hist
    size_t o_gbase = o_gt    + (size_t)NGRP * KB * 4;
    size_t o_bptr  = o_gbase + (size_t)NGRP * KB * 4;
    size_t o_epack = align16(o_bptr + ((size_t)KB + 1) * 4);
    size_t o_xb    = align16(o_epack + (size_t)E * 8);
    size_t need_f32  = o_xb;
    size_t need_bf16 = o_xb + (size_t)N * D_FEAT * 2;

    if (ws_size < need_f32) {
        hipMemsetAsync(d_out, 0, (size_t)out_size * sizeof(float), stream);
        const int grid = (E + 7) / 8;
        spmm_edge_atomic<<<grid, 256, 0, stream>>>(src, dst, att, X, out, E);
        return;
    }

    char* ws = (char*)d_ws;
    u16*  hist  = (u16*)(ws + o_hist);
    u32*  gt    = (u32*)(ws + o_gt);
    u32*  gbase = (u32*)(ws + o_gbase);
    u32*  bptr  = (u32*)(ws + o_bptr);
    int2* epack = (int2*)(ws + o_epack);
    uint2* Xb   = (uint2*)(ws + o_xb);

    const bool use_bf16 = (ws_size >= need_bf16);

    prep1<<<nchunk + (use_bf16 ? NCONV : 0), 512, 0, stream>>>(
        src, hist, E, nchunk, X, Xb, use_bf16 ? 1 : 0);
    colscan_a<<<(KB * NGRP + 255) / 256, 256, 0, stream>>>(hist, gt, nchunk, gsz);
    colscan_b<<<1, 1024, 0, stream>>>(gt, gbase, bptr);
    chunk_scatter<<<nchunk, 512, 0, stream>>>(src, dst, att, bptr, hist, gbase,
                                              epack, E, gsz);

    if (use_bf16)
        accumulate_stream_bf16<<<KB, 1024, 0, stream>>>(bptr, epack, Xb, out, N);
    else
        accumulate_stream_f32<<<KB, 1024, 0, stream>>>(bptr, epack, X, out, N);
}

// Round 6
// 355.530 us; speedup vs baseline: 7.9721x; 7.9721x over previous
//
#include <hip/hip_runtime.h>

typedef unsigned int u32;
typedef unsigned short u16;

// SpMM: out[src[e], :] += att[e] * X[dst[e], :]
// edges int32 (2,E): src = edges[0..E), dst = edges[E..2E)
//
// Round-11: combine best-measured halves + panel-keyed regroup.
//   - Accumulate: round-2 geometry (BROWS=64, KB=1563, 256 thr) = 162 us,
//     with the regroup placement key extended to (row*8 | dst>>14): ebuf
//     becomes row-major / dst-panel-minor, so gathers walk 4MB panels of
//     Xb in order (L2-affine). Scatter is untouched.
//   - Prep: round-4 structure (CHUNK=4096 -> 782 blocks, u16 hist matrix,
//     8-way colscan) = ~178 us, keyed at KB=1563.
//   - DEAD END (rounds 3+5): streaming accumulate with LDS atomics
//     (both atomicAdd-on-shared and raw ds_add_f32) runs ~15x slower at
//     identical fetch volume; dense LDS atomics poison the memory pipe.

constexpr int D_FEAT  = 128;
constexpr int N_NODES = 100000;
constexpr int BROWS   = 64;
constexpr int KB      = (N_NODES + BROWS - 1) / BROWS;   // 1563
constexpr int CHUNK   = 4096;
constexpr int NGRP    = 8;      // colscan chunk groups
constexpr int NCONV   = 256;    // extra blocks in prep1 doing X->bf16
constexpr int CAP     = 2560;   // bucket mean 2048, sigma ~45 -> +11 sigma
constexpr int NPAN    = 8;      // dst panels (dst>>14): 16384 nodes = 4MB Xb
constexpr int NCELL   = BROWS * NPAN;   // 512 regroup cells

__device__ __forceinline__ u32 rne_bf16(float f) {
    u32 u = __float_as_uint(f);
    return (u + 0x7FFFu + ((u >> 16) & 1u)) >> 16;
}

// ---------- 1: fused per-chunk histogram (u16) + X -> bf16 ----------
__global__ __launch_bounds__(512) void prep1(const int* __restrict__ src,
                                             u16* __restrict__ hist, int E, int nchunk,
                                             const float* __restrict__ X,
                                             uint2* __restrict__ Xb, int do_conv) {
    __shared__ u32 h[KB];
    const int blk = blockIdx.x;
    if (blk < nchunk) {
        const int e0 = blk * CHUNK;
        const int e1 = min(e0 + CHUNK, E);
        const int n  = e1 - e0;
        const int nfull = n & ~3;
        for (int i = threadIdx.x; i < KB; i += 512) h[i] = 0;
        __syncthreads();
        for (int o = threadIdx.x * 4; o < nfull; o += 2048) {
            int4 s4 = *(const int4*)(src + e0 + o);
            atomicAdd(&h[s4.x >> 6], 1u);
            atomicAdd(&h[s4.y >> 6], 1u);
            atomicAdd(&h[s4.z >> 6], 1u);
            atomicAdd(&h[s4.w >> 6], 1u);
        }
        for (int o = nfull + threadIdx.x; o < n; o += 512)
            atomicAdd(&h[src[e0 + o] >> 6], 1u);
        __syncthreads();
        u16* row = hist + (size_t)blk * KB;
        for (int i = threadIdx.x; i < KB; i += 512) row[i] = (u16)h[i];
    } else if (do_conv) {
        const int nthreads = (gridDim.x - nchunk) * 512;
        const float4* __restrict__ X4 = (const float4*)X;
        for (int u = (blk - nchunk) * 512 + threadIdx.x; u < N_NODES * 32;
             u += nthreads) {
            float4 v = X4[u];
            uint2 o;
            o.x = rne_bf16(v.x) | (rne_bf16(v.y) << 16);
            o.y = rne_bf16(v.z) | (rne_bf16(v.w) << 16);
            Xb[u] = o;
        }
    }
}

// ---------- 2a: per-(bucket, group) prefix over its chunk range ----------
__global__ __launch_bounds__(256) void colscan_a(u16* __restrict__ hist,
                                                 u32* __restrict__ gt,
                                                 int nchunk, int gsz) {
    const int t = blockIdx.x * 256 + threadIdx.x;
    if (t >= KB * NGRP) return;
    const int g = t / KB;
    const int b = t - g * KB;
    const int c0 = g * gsz;
    const int c1 = min(c0 + gsz, nchunk);
    u32 run = 0;
    int c = c0;
    for (; c + 4 <= c1; c += 4) {
        u32 v0 = hist[(size_t)(c + 0) * KB + b];
        u32 v1 = hist[(size_t)(c + 1) * KB + b];
        u32 v2 = hist[(size_t)(c + 2) * KB + b];
        u32 v3 = hist[(size_t)(c + 3) * KB + b];
        hist[(size_t)(c + 0) * KB + b] = (u16)run;
        hist[(size_t)(c + 1) * KB + b] = (u16)(run + v0);
        hist[(size_t)(c + 2) * KB + b] = (u16)(run + v0 + v1);
        hist[(size_t)(c + 3) * KB + b] = (u16)(run + v0 + v1 + v2);
        run += v0 + v1 + v2 + v3;
    }
    for (; c < c1; ++c) {
        u32 v = hist[(size_t)c * KB + b];
        hist[(size_t)c * KB + b] = (u16)run;
        run += v;
    }
    gt[(size_t)g * KB + b] = run;
}

// ---------- 2b (1 block): group bases + exclusive bucket scan (KB<=2048) ----------
__global__ __launch_bounds__(1024) void colscan_b(const u32* __restrict__ gt,
                                                  u32* __restrict__ gbase,
                                                  u32* __restrict__ bptr) {
    __shared__ u32 sm[1024];
    const int t = threadIdx.x;
    const int i0 = 2 * t, i1 = 2 * t + 1;
    u32 tot0 = 0, tot1 = 0;
    #pragma unroll
    for (int g = 0; g < NGRP; ++g) {
        if (i0 < KB) { u32 v = gt[(size_t)g * KB + i0]; gbase[(size_t)g * KB + i0] = tot0; tot0 += v; }
        if (i1 < KB) { u32 v = gt[(size_t)g * KB + i1]; gbase[(size_t)g * KB + i1] = tot1; tot1 += v; }
    }
    u32 ts = tot0 + tot1;
    sm[t] = ts;
    __syncthreads();
    for (int o = 1; o < 1024; o <<= 1) {
        u32 v = (t >= o) ? sm[t - o] : 0u;
        __syncthreads();
        sm[t] += v;
        __syncthreads();
    }
    u32 excl = sm[t] - ts;
    if (i0 < KB) bptr[i0] = excl;
    if (i1 < KB) bptr[i1] = excl + tot0;
    if (t == 1023) bptr[KB] = sm[1023];
}

// ---------- 3: scatter with precomputed LDS cursors ----------
__global__ __launch_bounds__(512) void chunk_scatter(const int* __restrict__ src,
                                                     const int* __restrict__ dst,
                                                     const float* __restrict__ att,
                                                     const u32* __restrict__ bptr,
                                                     const u16* __restrict__ hist,
                                                     const u32* __restrict__ gbase,
                                                     int2* __restrict__ epack,
                                                     int E, int gsz) {
    __shared__ u32 cur[KB];
    const int c  = blockIdx.x;
    const int e0 = c * CHUNK;
    const int e1 = min(e0 + CHUNK, E);
    const int n  = e1 - e0;
    const int nfull = n & ~3;
    const u16* hrow = hist + (size_t)c * KB;
    const u32* grow = gbase + (size_t)(c / gsz) * KB;
    for (int i = threadIdx.x; i < KB; i += 512)
        cur[i] = bptr[i] + grow[i] + (u32)hrow[i];
    __syncthreads();
    const bool v4ok = ((E & 3) == 0);   // dst = edges+E alignment for int4
    if (v4ok) {
        for (int o = threadIdx.x * 4; o < nfull; o += 2048) {
            int4   s4 = *(const int4*)(src + e0 + o);
            int4   d4 = *(const int4*)(dst + e0 + o);
            float4 a4 = *(const float4*)(att + e0 + o);
            #pragma unroll
            for (int k = 0; k < 4; ++k) {
                int s = (&s4.x)[k];
                u32 pos = atomicAdd(&cur[s >> 6], 1u);
                epack[pos] = make_int2(((s & 63) << 17) | (&d4.x)[k],
                                       __float_as_int((&a4.x)[k]));
            }
        }
        for (int o = nfull + threadIdx.x; o < n; o += 512) {
            int s = src[e0 + o];
            u32 pos = atomicAdd(&cur[s >> 6], 1u);
            epack[pos] = make_int2(((s & 63) << 17) | dst[e0 + o],
                                   __float_as_int(att[e0 + o]));
        }
    } else {
        for (int o = threadIdx.x; o < n; o += 512) {
            int s = src[e0 + o];
            u32 pos = atomicAdd(&cur[s >> 6], 1u);
            epack[pos] = make_int2(((s & 63) << 17) | dst[e0 + o],
                                   __float_as_int(att[e0 + o]));
        }
    }
}

// ---------- regroup: cells = row*8 | dst-panel; 4B ebuf (dst17|att_q15) ----------
#define REGROUP_BODY()                                                         \
    for (int i = tid; i < NCELL; i += 256) cnt[i] = 0;                         \
    __syncthreads();                                                           \
    for (int i = tid; i < nb; i += 256) {                                      \
        u32 x = (u32)epack[s + i].x;                                           \
        atomicAdd(&cnt[((x >> 17) << 3) | ((x & 0x1FFFFu) >> 14)], 1u);        \
    }                                                                          \
    __syncthreads();                                                           \
    if (tid < 64) {                                                            \
        u32 c[8]; u32 tot = 0;                                                 \
        _Pragma("unroll")                                                      \
        for (int k = 0; k < 8; ++k) { c[k] = cnt[tid * 8 + k]; tot += c[k]; }  \
        u32 incl = tot;                                                        \
        _Pragma("unroll")                                                      \
        for (int o = 1; o < 64; o <<= 1) {                                     \
            u32 v = __shfl_up(incl, o, 64);                                    \
            if (tid >= o) incl += v;                                           \
        }                                                                      \
        u32 run = incl - tot;                                                  \
        _Pragma("unroll")                                                      \
        for (int k = 0; k < 8; ++k) {                                          \
            off[tid * 8 + k] = run; cur[tid * 8 + k] = run; run += c[k];       \
        }                                                                      \
        if (tid == 63) off[NCELL] = run;                                       \
    }                                                                          \
    __syncthreads();                                                           \
    for (int i = tid; i < nb; i += 256) {                                      \
        int2 p = epack[s + i];                                                 \
        u32 x = (u32)p.x;                                                      \
        float af = __int_as_float(p.y);                                        \
        u32 q = (u32)(af * 32768.0f + 0.5f);                                   \
        q = min(q, 32767u);                                                    \
        u32 pos = atomicAdd(&cur[((x >> 17) << 3) | ((x & 0x1FFFFu) >> 14)], 1u); \
        ebuf[pos] = ((x & 0x1FFFFu) << 15) | q;                                \
    }                                                                          \
    __syncthreads();

// ---------- 4 (bf16): per-bucket regroup + 32-lane bf16 gather ----------
__global__ __launch_bounds__(256) void accumulate_bucket_bf16(
    const u32* __restrict__ bptr, const int2* __restrict__ epack,
    const uint2* __restrict__ Xb, const float* __restrict__ X,
    float* __restrict__ out, int N)
{
    __shared__ u32 ebuf[CAP];
    __shared__ u32 cnt[NCELL], cur[NCELL];
    __shared__ u32 off[NCELL + 1];
    const int b   = blockIdx.x;
    const int tid = threadIdx.x;
    const int g   = tid >> 5;
    const int l   = tid & 31;
    const u32 s = bptr[b], e = bptr[b + 1];
    const int nb = (int)(e - s);
    const int row0 = b * BROWS;
    const int rows = min(BROWS, N - row0);

    if (nb > CAP) {
        // Degenerate overflow path: zero rows, then fp32 edge atomics.
        float4* o4 = (float4*)(out + (size_t)row0 * D_FEAT);
        for (int i = tid; i < rows * 32; i += 256) o4[i] = make_float4(0.f,0.f,0.f,0.f);
        __syncthreads();
        for (u32 k = s + g; k < e; k += 8) {
            int2 p = epack[k];
            int d = p.x & 0x1FFFF, sl = (u32)p.x >> 17;
            float a = __int_as_float(p.y);
            float4 v = ((const float4*)(X + (size_t)d * D_FEAT))[l];
            float* o = out + (size_t)(row0 + sl) * D_FEAT + l * 4;
            unsafeAtomicAdd(o + 0, a * v.x);
            unsafeAtomicAdd(o + 1, a * v.y);
            unsafeAtomicAdd(o + 2, a * v.z);
            unsafeAtomicAdd(o + 3, a * v.w);
        }
        return;
    }

    REGROUP_BODY()

    // one 32-lane group per row: uint2 = 4 bf16 per lane, unroll-8;
    // row r's edges are [off[8r], off[8r+8]) — panel-ordered within the row.
    for (int r = g; r < rows; r += 8) {
        const u32 base = off[r << 3];
        const u32 n    = off[(r << 3) + 8] - base;
        float4 acc = make_float4(0.f, 0.f, 0.f, 0.f);
        u32 j = 0;
        for (; j + 8 <= n; j += 8) {
            u32 p[8]; uint2 q[8];
            #pragma unroll
            for (int k = 0; k < 8; ++k) p[k] = ebuf[base + j + k];
            #pragma unroll
            for (int k = 0; k < 8; ++k) q[k] = Xb[(size_t)(p[k] >> 15) * 32 + l];
            #pragma unroll
            for (int k = 0; k < 8; ++k) {
                const float a = (float)(p[k] & 0x7FFFu) * (1.0f / 32768.0f);
                acc.x = fmaf(a, __uint_as_float(q[k].x << 16),          acc.x);
                acc.y = fmaf(a, __uint_as_float(q[k].x & 0xFFFF0000u),  acc.y);
                acc.z = fmaf(a, __uint_as_float(q[k].y << 16),          acc.z);
                acc.w = fmaf(a, __uint_as_float(q[k].y & 0xFFFF0000u),  acc.w);
            }
        }
        for (; j + 2 <= n; j += 2) {
            const u32 p0 = ebuf[base + j];
            const u32 p1 = ebuf[base + j + 1];
            const uint2 q0 = Xb[(size_t)(p0 >> 15) * 32 + l];
            const uint2 q1 = Xb[(size_t)(p1 >> 15) * 32 + l];
            const float a0 = (float)(p0 & 0x7FFFu) * (1.0f / 32768.0f);
            const float a1 = (float)(p1 & 0x7FFFu) * (1.0f / 32768.0f);
            acc.x = fmaf(a0, __uint_as_float(q0.x << 16),         acc.x);
            acc.y = fmaf(a0, __uint_as_float(q0.x & 0xFFFF0000u), acc.y);
            acc.z = fmaf(a0, __uint_as_float(q0.y << 16),         acc.z);
            acc.w = fmaf(a0, __uint_as_float(q0.y & 0xFFFF0000u), acc.w);
            acc.x = fmaf(a1, __uint_as_float(q1.x << 16),         acc.x);
            acc.y = fmaf(a1, __uint_as_float(q1.x & 0xFFFF0000u), acc.y);
            acc.z = fmaf(a1, __uint_as_float(q1.y << 16),         acc.z);
            acc.w = fmaf(a1, __uint_as_float(q1.y & 0xFFFF0000u), acc.w);
        }
        if (j < n) {
            const u32 p = ebuf[base + j];
            const uint2 q = Xb[(size_t)(p >> 15) * 32 + l];
            const float a = (float)(p & 0x7FFFu) * (1.0f / 32768.0f);
            acc.x = fmaf(a, __uint_as_float(q.x << 16),         acc.x);
            acc.y = fmaf(a, __uint_as_float(q.x & 0xFFFF0000u), acc.y);
            acc.z = fmaf(a, __uint_as_float(q.y << 16),         acc.z);
            acc.w = fmaf(a, __uint_as_float(q.y & 0xFFFF0000u), acc.w);
        }
        ((float4*)out)[(size_t)(row0 + r) * 32 + l] = acc;
    }
}

// ---------- 4 (fp32): fallback when ws can't hold Xb ----------
__global__ __launch_bounds__(256) void accumulate_bucket_f32(
    const u32* __restrict__ bptr, const int2* __restrict__ epack,
    const float* __restrict__ X, float* __restrict__ out, int N)
{
    __shared__ u32 ebuf[CAP];
    __shared__ u32 cnt[NCELL], cur[NCELL];
    __shared__ u32 off[NCELL + 1];
    const int b   = blockIdx.x;
    const int tid = threadIdx.x;
    const int g   = tid >> 5;
    const int l   = tid & 31;
    const u32 s = bptr[b], e = bptr[b + 1];
    const int nb = (int)(e - s);
    const int row0 = b * BROWS;
    const int rows = min(BROWS, N - row0);

    if (nb > CAP) {
        float4* o4 = (float4*)(out + (size_t)row0 * D_FEAT);
        for (int i = tid; i < rows * 32; i += 256) o4[i] = make_float4(0.f,0.f,0.f,0.f);
        __syncthreads();
        for (u32 k = s + g; k < e; k += 8) {
            int2 p = epack[k];
            int d = p.x & 0x1FFFF, sl = (u32)p.x >> 17;
            float a = __int_as_float(p.y);
            float4 v = ((const float4*)(X + (size_t)d * D_FEAT))[l];
            float* o = out + (size_t)(row0 + sl) * D_FEAT + l * 4;
            unsafeAtomicAdd(o + 0, a * v.x);
            unsafeAtomicAdd(o + 1, a * v.y);
            unsafeAtomicAdd(o + 2, a * v.z);
            unsafeAtomicAdd(o + 3, a * v.w);
        }
        return;
    }

    REGROUP_BODY()

    const float4* __restrict__ X4 = (const float4*)X;
    for (int r = g; r < rows; r += 8) {
        const u32 base = off[r << 3];
        const u32 n    = off[(r << 3) + 8] - base;
        float4 acc = make_float4(0.f, 0.f, 0.f, 0.f);
        u32 j = 0;
        for (; j + 4 <= n; j += 4) {
            u32 p[4]; float4 v[4];
            #pragma unroll
            for (int k = 0; k < 4; ++k) p[k] = ebuf[base + j + k];
            #pragma unroll
            for (int k = 0; k < 4; ++k) v[k] = X4[(size_t)(p[k] >> 15) * 32 + l];
            #pragma unroll
            for (int k = 0; k < 4; ++k) {
                const float a = (float)(p[k] & 0x7FFFu) * (1.0f / 32768.0f);
                acc.x = fmaf(a, v[k].x, acc.x); acc.y = fmaf(a, v[k].y, acc.y);
                acc.z = fmaf(a, v[k].z, acc.z); acc.w = fmaf(a, v[k].w, acc.w);
            }
        }
        for (; j < n; ++j) {
            const u32 p = ebuf[base + j];
            const float4 v = X4[(size_t)(p >> 15) * 32 + l];
            const float a = (float)(p & 0x7FFFu) * (1.0f / 32768.0f);
            acc.x = fmaf(a, v.x, acc.x); acc.y = fmaf(a, v.y, acc.y);
            acc.z = fmaf(a, v.z, acc.z); acc.w = fmaf(a, v.w, acc.w);
        }
        ((float4*)out)[(size_t)(row0 + r) * 32 + l] = acc;
    }
}

// ---------- last-resort fallback: edge-parallel fp atomics ----------
__global__ __launch_bounds__(256) void spmm_edge_atomic(
    const int* __restrict__ src, const int* __restrict__ dst,
    const float* __restrict__ att, const float* __restrict__ X,
    float* __restrict__ out, int E)
{
    const int group = (int)((blockIdx.x * blockDim.x + threadIdx.x) >> 5);
    const int lane  = threadIdx.x & 31;
    const int nGroups = (int)((gridDim.x * blockDim.x) >> 5);
    for (int e = group; e < E; e += nGroups) {
        const int s = src[e], d = dst[e];
        const float a = att[e];
        const float4 v = ((const float4*)(X + (size_t)d * D_FEAT))[lane];
        float* o = out + (size_t)s * D_FEAT + (size_t)lane * 4;
        unsafeAtomicAdd(o + 0, a * v.x);
        unsafeAtomicAdd(o + 1, a * v.y);
        unsafeAtomicAdd(o + 2, a * v.z);
        unsafeAtomicAdd(o + 3, a * v.w);
    }
}

static inline size_t align16(size_t x) { return (x + 15) & ~(size_t)15; }

extern "C" void kernel_launch(void* const* d_in, const int* in_sizes, int n_in,
                              void* d_out, int out_size, void* d_ws, size_t ws_size,
                              hipStream_t stream) {
    const int*   edges = (const int*)d_in[0];   // (2, E) int32
    const float* att   = (const float*)d_in[1]; // (E,)
    const float* X     = (const float*)d_in[3]; // (N, 128)
    float*       out   = (float*)d_out;

    const int E = in_sizes[1];
    const int N = N_NODES;
    const int* src = edges;
    const int* dst = edges + E;
    const int nchunk = (E + CHUNK - 1) / CHUNK;
    const int gsz    = (nchunk + NGRP - 1) / NGRP;

    size_t o_hist  = 0;
    size_t o_gt    = align16(o_hist + (size_t)nchunk * KB * 2);   // u16 hist
    size_t o_gbase = o_gt    + (size_t)NGRP * KB * 4;
    size_t o_bptr  = o_gbase + (size_t)NGRP * KB * 4;
    size_t o_epack = align16(o_bptr + ((size_t)KB + 1) * 4);
    size_t o_xb    = align16(o_epack + (size_t)E * 8);
    size_t need_f32  = o_xb;
    size_t need_bf16 = o_xb + (size_t)N * D_FEAT * 2;

    if (ws_size < need_f32) {
        hipMemsetAsync(d_out, 0, (size_t)out_size * sizeof(float), stream);
        const int grid = (E + 7) / 8;
        spmm_edge_atomic<<<grid, 256, 0, stream>>>(src, dst, att, X, out, E);
        return;
    }

    char* ws = (char*)d_ws;
    u16*  hist  = (u16*)(ws + o_hist);
    u32*  gt    = (u32*)(ws + o_gt);
    u32*  gbase = (u32*)(ws + o_gbase);
    u32*  bptr  = (u32*)(ws + o_bptr);
    int2* epack = (int2*)(ws + o_epack);
    uint2* Xb   = (uint2*)(ws + o_xb);

    const bool use_bf16 = (ws_size >= need_bf16);

    prep1<<<nchunk + (use_bf16 ? NCONV : 0), 512, 0, stream>>>(
        src, hist, E, nchunk, X, Xb, use_bf16 ? 1 : 0);
    colscan_a<<<(KB * NGRP + 255) / 256, 256, 0, stream>>>(hist, gt, nchunk, gsz);
    colscan_b<<<1, 1024, 0, stream>>>(gt, gbase, bptr);
    chunk_scatter<<<nchunk, 512, 0, stream>>>(src, dst, att, bptr, hist, gbase,
                                              epack, E, gsz);

    if (use_bf16)
        accumulate_bucket_bf16<<<KB, 256, 0, stream>>>(bptr, epack, Xb, X, out, N);
    else
        accumulate_bucket_f32<<<KB, 256, 0, stream>>>(bptr, epack, X, out, N);
}